// Round 5
// baseline (1847.928 us; speedup 1.0000x reference)
//
#include <hip/hip_runtime.h>
#include <stdint.h>

#define BB 16
#define EE 256
#define TT 4096
#define FF 512
#define RK 10
#define NIT 5

typedef short bf16x8 __attribute__((ext_vector_type(8)));
typedef float f32x4  __attribute__((ext_vector_type(4)));

__device__ __forceinline__ unsigned short f2bf(float x){
  unsigned int u = __float_as_uint(x);
  unsigned int r = (u + 0x7FFFu + ((u >> 16) & 1u)) >> 16;
  return (unsigned short)r;
}
__device__ __forceinline__ float bf2f(unsigned short s){
  return __uint_as_float(((unsigned int)s) << 16);
}

// async global->LDS, 16B per lane; LDS dest linear in lane order.
__device__ __forceinline__ void gld16(const void* g, void* l){
  __builtin_amdgcn_global_load_lds((const __attribute__((address_space(1))) unsigned int*)g,
                                   (__attribute__((address_space(3))) unsigned int*)l,
                                   16, 0, 0);
}

// slot swizzle (involution): source slot for (row r, phys slot s), ushort units
__device__ __forceinline__ int ssw(int r, int s){
  return ((s ^ (r & 3) ^ ((r >> 2) & 3)) << 3);
}

// ---------------- setup kernels ----------------

__global__ void k_params(const float* lam_log, const float* mu_log,
                         const float* nu_log, const float* gl, float* prm){
  int k = threadIdx.x;
  if (k < NIT){
    float lam = expf(lam_log[k]);
    float mu  = expf(mu_log[k]);
    float nu  = expf(nu_log[k]);
    float gam = 1.0f/(1.0f+expf(-gl[k]));
    prm[k*8+0]=lam; prm[k*8+1]=mu; prm[k*8+2]=nu; prm[k*8+3]=gam; prm[k*8+4]=lam/nu;
  }
}

// Xb = bf16(Om*Y) ; also emit Omega as bf16 (binary -> exact)
__global__ void k_initX(const float4* __restrict__ Y, const float4* __restrict__ Om,
                        ushort4* __restrict__ Xb, ushort4* __restrict__ Omb){
  int i = blockIdx.x*256 + threadIdx.x;
  float4 y = Y[i], o = Om[i];
  ushort4 xb; xb.x=f2bf(y.x*o.x); xb.y=f2bf(y.y*o.y); xb.z=f2bf(y.z*o.z); xb.w=f2bf(y.w*o.w);
  Xb[i] = xb;
  ushort4 ob; ob.x=f2bf(o.x); ob.y=f2bf(o.y); ob.z=f2bf(o.z); ob.w=f2bf(o.w);
  Omb[i] = ob;
}

// Omega -> 1 bit/elem, [b][e][t] order, little-endian within u32 word
__global__ void k_ombit(const float* __restrict__ Om, unsigned int* __restrict__ Ombit){
  int tid = threadIdx.x;
  int wv = tid >> 6, lane = tid & 63;
  size_t base = (size_t)blockIdx.x*8192 + (size_t)wv*2048;
  for (int it=0; it<32; ++it){
    float om = Om[base + it*64 + lane];
    unsigned long long m = __ballot(om != 0.0f);
    if (lane==0)  Ombit[(base>>5) + it*2]     = (unsigned int)m;
    if (lane==32) Ombit[(base>>5) + it*2 + 1] = (unsigned int)(m>>32);
  }
}

__global__ void k_qtrans(const float* __restrict__ Q0, float* __restrict__ Qt){
  int idx = blockIdx.x*256 + threadIdx.x;   // b*TT + t
  int b = idx >> 12, t = idx & (TT-1);
  #pragma unroll
  for (int j=0;j<RK;j++)
    Qt[((size_t)b*RK + j)*TT + t] = Q0[(size_t)idx*RK + j];
}

// R -> bf16 [e][f] (binary, exact)  (B-operand of gemm1m)
__global__ void k_rbf(const float4* __restrict__ R, ushort4* __restrict__ Rb){
  int i = blockIdx.x*256 + threadIdx.x;
  float4 v = R[i];
  ushort4 o; o.x=f2bf(v.x); o.y=f2bf(v.y); o.z=f2bf(v.z); o.w=f2bf(v.w);
  Rb[i] = o;
}

// R -> bf16 transposed [f][e]  (B-operand of gemm2m/ascalem)
__global__ void k_rtransb(const float* __restrict__ Rm, unsigned short* __restrict__ Rbt){
  int f = blockIdx.x, b = blockIdx.y, e = threadIdx.x;
  Rbt[((size_t)b*FF + f)*EE + e] = f2bf(Rm[((size_t)b*EE + e)*FF + f]);
}

// Omb [e][t] -> OmbT [t][e], bf16 64x64 tile transpose (one-time)
__global__ void k_omtrans(const unsigned short* __restrict__ Omb,
                          unsigned short* __restrict__ OmbT){
  __shared__ unsigned short sT[64][66];
  int b  = blockIdx.z;
  int E0 = blockIdx.y*64, T0 = blockIdx.x*64;
  int tid = threadIdx.x;
  int fi = tid >> 4;          // 0..15
  int m  = tid & 15;
  #pragma unroll
  for (int pass=0; pass<4; ++pass){
    int e = pass*16 + fi;
    ushort4 v = *(const ushort4*)(Omb + ((size_t)(b*EE + E0 + e))*TT + T0 + m*4);
    sT[e][m*4+0]=v.x; sT[e][m*4+1]=v.y; sT[e][m*4+2]=v.z; sT[e][m*4+3]=v.w;
  }
  __syncthreads();
  #pragma unroll
  for (int pass=0; pass<4; ++pass){
    int t  = pass*16 + fi;
    int e4 = m*4;
    ushort4 o;
    o.x = sT[e4+0][t]; o.y = sT[e4+1][t];
    o.z = sT[e4+2][t]; o.w = sT[e4+3][t];
    *(ushort4*)(OmbT + ((size_t)b*TT + T0 + t)*EE + E0 + e4) = o;
  }
}

// ---------------- per-iteration small kernels ----------------

__global__ void k_lhsQ(const float* __restrict__ Qt, const float* __restrict__ prm,
                       float* __restrict__ lhs, int k){
  int p = blockIdx.x, b = blockIdx.y;
  int i = 0, rem = p;
  while (rem >= i+1){ rem -= (i+1); ++i; }
  int j = rem;
  const float* qi = Qt + ((size_t)b*RK + i)*TT;
  const float* qj = Qt + ((size_t)b*RK + j)*TT;
  float a = 0.0f;
  for (int t = threadIdx.x*4; t < TT; t += 1024){
    float4 x = *(const float4*)(qi+t);
    float4 y = *(const float4*)(qj+t);
    a += x.x*y.x + x.y*y.y + x.z*y.z + x.w*y.w;
  }
  __shared__ float red[256];
  red[threadIdx.x] = a; __syncthreads();
  for (int s=128; s>0; s>>=1){
    if (threadIdx.x < s) red[threadIdx.x] += red[threadIdx.x+s];
    __syncthreads();
  }
  if (threadIdx.x==0){
    float v = red[0];
    if (i==j) v += prm[k*8+4];
    lhs[(b*RK+i)*RK + j] = v;
    lhs[(b*RK+j)*RK + i] = v;
  }
}

__global__ void k_lhsP(const float* __restrict__ P, const float* __restrict__ prm,
                       float* __restrict__ lhs, int k){
  int p = blockIdx.x, b = blockIdx.y;
  int i = 0, rem = p;
  while (rem >= i+1){ rem -= (i+1); ++i; }
  int j = rem;
  int e = threadIdx.x;
  const float* pr = P + ((size_t)b*EE + e)*RK;
  float a = pr[i]*pr[j];
  __shared__ float red[256];
  red[threadIdx.x] = a; __syncthreads();
  for (int s=128; s>0; s>>=1){
    if (threadIdx.x < s) red[threadIdx.x] += red[threadIdx.x+s];
    __syncthreads();
  }
  if (threadIdx.x==0){
    float v = red[0];
    if (i==j) v += prm[k*8+4];
    lhs[(b*RK+i)*RK + j] = v;
    lhs[(b*RK+j)*RK + i] = v;
  }
}

__global__ void k_invert(const float* __restrict__ lhs, float* __restrict__ inv){
  int b = blockIdx.x;
  __shared__ float aug[RK][2*RK];
  int tid = threadIdx.x;
  int i = tid / (2*RK), j = tid % (2*RK);
  bool act = tid < RK*2*RK;
  if (act) aug[i][j] = (j < RK) ? lhs[(b*RK+i)*RK + j] : ((j-RK)==i ? 1.0f : 0.0f);
  __syncthreads();
  for (int kk=0; kk<RK; ++kk){
    float pinv = 1.0f / aug[kk][kk];
    __syncthreads();
    if (act && i==kk) aug[i][j] *= pinv;
    __syncthreads();
    float factor = (act && i!=kk) ? aug[i][kk] : 0.0f;
    float pivrow = act ? aug[kk][j] : 0.0f;
    __syncthreads();
    if (act && i!=kk) aug[i][j] -= factor * pivrow;
    __syncthreads();
  }
  if (act && j >= RK) inv[(b*RK+i)*RK + (j-RK)] = aug[i][j];
}

// Pupd: P = (X@Q)@inv, X read as bf16 [e][t]
__global__ void k_Pupd(const unsigned short* __restrict__ Xb, const float* __restrict__ Qt,
                       const float* __restrict__ inv, float* __restrict__ P){
  int e = blockIdx.x, b = blockIdx.y;
  const unsigned short* xr = Xb + ((size_t)b*EE + e)*TT;
  const float* qb = Qt + (size_t)b*RK*TT;
  float acc[RK];
  #pragma unroll
  for (int j=0;j<RK;j++) acc[j]=0.0f;
  for (int t = threadIdx.x*8; t < TT; t += 2048){
    bf16x8 xv = *(const bf16x8*)(xr+t);
    float xf[8];
    #pragma unroll
    for (int i=0;i<8;++i) xf[i] = bf2f((unsigned short)xv[i]);
    #pragma unroll
    for (int j=0;j<RK;j++){
      float4 qa = *(const float4*)(qb + (size_t)j*TT + t);
      float4 qc = *(const float4*)(qb + (size_t)j*TT + t + 4);
      acc[j] += xf[0]*qa.x + xf[1]*qa.y + xf[2]*qa.z + xf[3]*qa.w
              + xf[4]*qc.x + xf[5]*qc.y + xf[6]*qc.z + xf[7]*qc.w;
    }
  }
  __shared__ float partial[4][RK];
  int lane = threadIdx.x & 63, wv = threadIdx.x >> 6;
  #pragma unroll
  for (int j=0;j<RK;j++){
    float v = acc[j];
    for (int s=32;s>0;s>>=1) v += __shfl_down(v, s, 64);
    if (lane==0) partial[wv][j] = v;
  }
  __syncthreads();
  if (threadIdx.x < RK){
    int i = threadIdx.x;
    float out = 0.0f;
    #pragma unroll
    for (int j=0;j<RK;j++){
      float xq = partial[0][j]+partial[1][j]+partial[2][j]+partial[3][j];
      out += xq * inv[(b*RK+j)*RK + i];
    }
    P[((size_t)b*EE + e)*RK + i] = out;
  }
}

// Qupd: Q = (X^T@P)@inv, X read as bf16
__global__ void k_Qupd(const unsigned short* __restrict__ Xb, const float* __restrict__ P,
                       const float* __restrict__ inv, float* __restrict__ Qt){
  int b = blockIdx.y;
  int t = blockIdx.x*256 + threadIdx.x;
  __shared__ float sP[EE*RK];
  __shared__ float sInv[RK*RK];
  for (int i=threadIdx.x; i<EE*RK; i+=256) sP[i] = P[(size_t)b*EE*RK + i];
  if (threadIdx.x < RK*RK) sInv[threadIdx.x] = inv[b*RK*RK + threadIdx.x];
  __syncthreads();
  float acc[RK];
  #pragma unroll
  for (int j=0;j<RK;j++) acc[j]=0.0f;
  const unsigned short* xb = Xb + (size_t)b*EE*TT + t;
  for (int e=0;e<EE;e++){
    float x = bf2f(xb[(size_t)e*TT]);
    #pragma unroll
    for (int j=0;j<RK;j++) acc[j] += x * sP[e*RK+j];
  }
  #pragma unroll
  for (int i=0;i<RK;i++){
    float q = 0.0f;
    #pragma unroll
    for (int j=0;j<RK;j++) q += acc[j]*sInv[j*RK+i];
    Qt[((size_t)b*RK + i)*TT + t] = q;
  }
}

// ---------------- fused MFMA gemm1 (M=t 64, N=e 128), double-buffered K-loop ----
// A-operand = Abt [t][f], B-operand = Rb [e][f]; D[t][e] = RA[e][t].
// Writes Xb bf16 [e][t] and residT bf16 [t][e] (per-wave LDS quadrant transpose).
__global__ __launch_bounds__(256) void k_gemm1m(
    const unsigned short* __restrict__ Abt, const unsigned short* __restrict__ Rb,
    const float* __restrict__ Y, const unsigned int* __restrict__ Ombit,
    const float* __restrict__ Qt, const float* __restrict__ P,
    const float* __restrict__ prm, unsigned short* __restrict__ Xb,
    unsigned short* __restrict__ residT, int k)
{
  __shared__ __align__(16) unsigned char lds[32768];   // 2x12K staging + P/Q
  int id = blockIdx.x;                 // 2048 = b(16) x e-tile(2) x t-tile(64)
  int b  = id >> 7;
  int e0 = ((id >> 6) & 1) * 128;
  int t0 = (id & 63) * 64;
  int tid  = threadIdx.x;
  int lane = tid & 63, wid = tid >> 6;
  int lr = lane & 15, lg = lane >> 4;
  int wm = wid >> 1, wn = wid & 1;     // wm: t-half(32), wn: e-half(64)

  f32x4 acc[2][4];
  #pragma unroll
  for (int m=0;m<2;++m)
    #pragma unroll
    for (int n=0;n<4;++n)
      #pragma unroll
      for (int i=0;i<4;++i) acc[m][n][i]=0.0f;

  if (k > 0){
    int swz  = ((lg ^ (lr & 3) ^ ((lr >> 2) & 3)) << 4);
    int aoff = (wm*32 + lr)*64 + swz;            // A region: 64 t-rows @ buf+0
    int boff = 4096 + (wn*64 + lr)*64 + swz;     // B region: 128 e-rows @ buf+4096
    int rA = tid >> 2, sA = tid & 3;             // A: 256 chunks
    int c0 = tid, c1 = tid + 256;                // B: 512 chunks
    int rB0 = c0 >> 2, sB0 = c0 & 3;
    int rB1 = c1 >> 2, sB1 = c1 & 3;
    const unsigned short* gA  = Abt + ((size_t)b*TT + t0 + rA)*FF + ssw(rA,sA);
    const unsigned short* gB0 = Rb  + ((size_t)(b*EE + e0 + rB0))*FF + ssw(rB0,sB0);
    const unsigned short* gB1 = Rb  + ((size_t)(b*EE + e0 + rB1))*FF + ssw(rB1,sB1);

    // prologue: stage tile 0 into buffer 0
    gld16(gA,  lds + tid*16);
    gld16(gB0, lds + 4096 + c0*16);
    gld16(gB1, lds + 4096 + c1*16);
    #pragma unroll
    for (int kk=0; kk<16; ++kk){
      int cur = (kk&1)*12288;
      if (kk < 15){
        int nxt = ((kk+1)&1)*12288;
        int f0k = (kk+1)*32;
        gld16(gA  + f0k, lds + nxt + tid*16);
        gld16(gB0 + f0k, lds + nxt + 4096 + c0*16);
        gld16(gB1 + f0k, lds + nxt + 4096 + c1*16);
        asm volatile("s_waitcnt vmcnt(3)" ::: "memory");   // tile kk landed
      } else {
        asm volatile("s_waitcnt vmcnt(0)" ::: "memory");
      }
      __syncthreads();
      bf16x8 af[2], bb[4];
      #pragma unroll
      for (int m=0;m<2;++m) af[m] = *(const bf16x8*)(lds + cur + aoff + m*1024);
      #pragma unroll
      for (int n=0;n<4;++n) bb[n] = *(const bf16x8*)(lds + cur + boff + n*1024);
      #pragma unroll
      for (int m=0;m<2;++m)
        #pragma unroll
        for (int n=0;n<4;++n)
          acc[m][n] = __builtin_amdgcn_mfma_f32_16x16x32_bf16(af[m], bb[n], acc[m][n], 0, 0, 0);
      __syncthreads();                 // ds_reads done before buffer reuse
    }
  }

  // epilogue: wbuf [16][68] ushort per wave (reuses staging LDS); P/Q at top.
  __syncthreads();
  unsigned short* wbuf = (unsigned short*)(lds + wid*2176);
  float* Pl = (float*)(lds + 24576);           // [128][RK]
  float* Ql = (float*)(lds + 24576 + 5120);    // [RK][64]
  for (int idx = tid; idx < 128*RK; idx += 256)
    Pl[idx] = P[((size_t)(b*EE + e0))*RK + idx];
  for (int idx = tid; idx < RK*64; idx += 256){
    int j = idx >> 6, t = idx & 63;
    Ql[idx] = Qt[((size_t)(b*RK + j))*TT + t0 + t];
  }
  __syncthreads();

  float nu = prm[k*8+2];
  #pragma unroll
  for (int m=0;m<2;++m){
    int tq = wm*32 + m*16 + lg*4;                // t offset within 64-tile
    float4 ql4[RK];
    #pragma unroll
    for (int j=0;j<RK;++j) ql4[j] = *(const float4*)(Ql + j*64 + tq);
    asm volatile("" ::: "memory");
    #pragma unroll
    for (int n=0;n<4;++n){
      int eloc = wn*64 + n*16 + lr;
      const float* pr = Pl + eloc*RK;
      float4 pq = {0,0,0,0};
      #pragma unroll
      for (int j=0;j<RK;++j){
        float pj = pr[j];
        pq.x += pj*ql4[j].x; pq.y += pj*ql4[j].y;
        pq.z += pj*ql4[j].z; pq.w += pj*ql4[j].w;
      }
      f32x4 ra = acc[m][n];
      size_t off = ((size_t)(b*EE + e0 + eloc))*TT + t0 + tq;
      float4 y = *(const float4*)(Y + off);
      unsigned int w = Ombit[off >> 5];
      int sh = (int)(off & 31);                  // tq aligned to 4, t0 to 64
      float rs0, rs1, rs2, rs3; ushort4 xb4;
      {
        float om2 = (w>>(sh+0))&1 ? 1.0f : 0.0f; float d = y.x - ra[0];
        float x = (om2*d + nu*pq.x)/(om2 + nu); rs0 = om2*(y.x - x - ra[0]); xb4.x = f2bf(x);
      }{
        float om2 = (w>>(sh+1))&1 ? 1.0f : 0.0f; float d = y.y - ra[1];
        float x = (om2*d + nu*pq.y)/(om2 + nu); rs1 = om2*(y.y - x - ra[1]); xb4.y = f2bf(x);
      }{
        float om2 = (w>>(sh+2))&1 ? 1.0f : 0.0f; float d = y.z - ra[2];
        float x = (om2*d + nu*pq.z)/(om2 + nu); rs2 = om2*(y.z - x - ra[2]); xb4.z = f2bf(x);
      }{
        float om2 = (w>>(sh+3))&1 ? 1.0f : 0.0f; float d = y.w - ra[3];
        float x = (om2*d + nu*pq.w)/(om2 + nu); rs3 = om2*(y.w - x - ra[3]); xb4.w = f2bf(x);
      }
      *(ushort4*)(Xb + off) = xb4;
      int wc = n*16 + lr;
      wbuf[(lg*4+0)*68 + wc] = f2bf(rs0);
      wbuf[(lg*4+1)*68 + wc] = f2bf(rs1);
      wbuf[(lg*4+2)*68 + wc] = f2bf(rs2);
      wbuf[(lg*4+3)*68 + wc] = f2bf(rs3);
    }
    asm volatile("" ::: "memory");
    // readback: 16 t-rows x 64 e, coalesced 128B rows
    #pragma unroll
    for (int j2=0;j2<4;++j2){
      int row = j2*4 + lg;
      int c4  = lr*4;
      ushort4 vv = *(const ushort4*)(wbuf + row*68 + c4);
      *(ushort4*)(residT + ((size_t)b*TT + t0 + wm*32 + m*16 + row)*EE + e0 + wn*64 + c4) = vv;
    }
    asm volatile("" ::: "memory");
  }
}

__device__ __forceinline__ float aupd(float a, float g, unsigned short asu,
                                      float mu, float gamma){
  float as = bf2f(asu);
  bool no = (as == 0.0f);
  float rs = 1.0f / (no ? 1.0f : as);
  float ba = a + g*rs;
  float ad = copysignf(fmaxf(fabsf(ba) - mu*rs, 0.0f), ba);
  if (no) ad = 0.0f;
  return a + gamma*(ad - a);
}

// ---------------- MFMA gemm2 (M=t 128, N=f 64), double-buffered K-loop ----------
// A-operand = residT [t][e], B-operand = Rbt [f][e]; D[t][f] = G[f][t].
// Emits Abt bf16 [t][f] for next iteration (skipped at last).
__global__ __launch_bounds__(256) void k_gemm2m(
    const unsigned short* __restrict__ residT, const unsigned short* __restrict__ Rbt,
    const unsigned short* __restrict__ As, const float* __restrict__ prm,
    float* __restrict__ A, unsigned short* __restrict__ Abt, int k)
{
  __shared__ __align__(16) unsigned char lds[24576];   // 2 x 12 KiB
  int id = blockIdx.x;                 // 4096 = b(16) x f-tile(8) x t-tile(32)
  int b  = id >> 8;
  int f0 = ((id >> 5) & 7) * 64;
  int t0 = (id & 31) * 128;
  int tid  = threadIdx.x;
  int lane = tid & 63, wid = tid >> 6;
  int lr = lane & 15, lg = lane >> 4;
  int wm = wid >> 1, wn = wid & 1;     // wm: t-half(64), wn: f-half(32)

  f32x4 acc[4][2];
  #pragma unroll
  for (int m=0;m<4;++m)
    #pragma unroll
    for (int n=0;n<2;++n)
      #pragma unroll
      for (int i=0;i<4;++i) acc[m][n][i]=0.0f;

  int swz  = ((lg ^ (lr & 3) ^ ((lr >> 2) & 3)) << 4);
  int aoff = (wm*64 + lr)*64 + swz;            // A region: 128 t-rows @ buf+0
  int boff = 8192 + (wn*32 + lr)*64 + swz;     // B region: 64 f-rows @ buf+8192
  int c0 = tid, c1 = tid + 256;                // A: 512 chunks
  int r0 = c0 >> 2, s0 = c0 & 3;
  int r1 = c1 >> 2, s1 = c1 & 3;
  int rB = tid >> 2, sB = tid & 3;             // B: 256 chunks
  const unsigned short* gA0 = residT + ((size_t)b*TT + t0 + r0)*EE + ssw(r0,s0);
  const unsigned short* gA1 = residT + ((size_t)b*TT + t0 + r1)*EE + ssw(r1,s1);
  const unsigned short* gB  = Rbt    + ((size_t)(b*FF + f0 + rB))*EE + ssw(rB,sB);

  // prologue: stage tile 0 into buffer 0
  gld16(gA0, lds + c0*16);
  gld16(gA1, lds + c1*16);
  gld16(gB,  lds + 8192 + tid*16);
  #pragma unroll
  for (int kk=0; kk<8; ++kk){
    int cur = (kk&1)*12288;
    if (kk < 7){
      int nxt = ((kk+1)&1)*12288;
      int eoff = (kk+1)*32;
      gld16(gA0 + eoff, lds + nxt + c0*16);
      gld16(gA1 + eoff, lds + nxt + c1*16);
      gld16(gB  + eoff, lds + nxt + 8192 + tid*16);
      asm volatile("s_waitcnt vmcnt(3)" ::: "memory");   // tile kk landed
    } else {
      asm volatile("s_waitcnt vmcnt(0)" ::: "memory");
    }
    __syncthreads();
    bf16x8 af[4], bb[2];
    #pragma unroll
    for (int m=0;m<4;++m) af[m] = *(const bf16x8*)(lds + cur + aoff + m*1024);
    #pragma unroll
    for (int n=0;n<2;++n) bb[n] = *(const bf16x8*)(lds + cur + boff + n*1024);
    #pragma unroll
    for (int m=0;m<4;++m)
      #pragma unroll
      for (int n=0;n<2;++n)
        acc[m][n] = __builtin_amdgcn_mfma_f32_16x16x32_bf16(af[m], bb[n], acc[m][n], 0, 0, 0);
    __syncthreads();                   // ds_reads done before buffer reuse
  }

  __syncthreads();                      // staging LDS reused as wbuf below
  unsigned short* wbuf = (unsigned short*)(lds + wid*1152);   // [16][36]
  float mu = prm[k*8+1], gamma = prm[k*8+3];
  bool emit = (k < NIT-1);
  #pragma unroll
  for (int m=0;m<4;++m){
    int tq = wm*64 + m*16 + lg*4;
    #pragma unroll
    for (int n=0;n<2;++n){
      int floc = wn*32 + n*16 + lr;
      size_t off = ((size_t)(b*FF + f0 + floc))*TT + t0 + tq;
      float4 a = *(const float4*)(A + off);
      ushort4 as4 = *(const ushort4*)(As + off);
      f32x4 g = acc[m][n];
      float4 an;
      an.x = aupd(a.x, g[0], as4.x, mu, gamma);
      an.y = aupd(a.y, g[1], as4.y, mu, gamma);
      an.z = aupd(a.z, g[2], as4.z, mu, gamma);
      an.w = aupd(a.w, g[3], as4.w, mu, gamma);
      *(float4*)(A + off) = an;
      if (emit){
        int wc = n*16 + lr;
        wbuf[(lg*4+0)*36 + wc] = f2bf(an.x);
        wbuf[(lg*4+1)*36 + wc] = f2bf(an.y);
        wbuf[(lg*4+2)*36 + wc] = f2bf(an.z);
        wbuf[(lg*4+3)*36 + wc] = f2bf(an.w);
      }
    }
    asm volatile("" ::: "memory");
    if (emit){
      // readback: 16 t-rows x 32 f, 2 passes of 8 rows x 8 lanes
      #pragma unroll
      for (int j2=0;j2<2;++j2){
        int row = j2*8 + (lane >> 3);
        int c4  = (lane & 7)*4;
        ushort4 vv = *(const ushort4*)(wbuf + row*36 + c4);
        *(ushort4*)(Abt + ((size_t)b*TT + t0 + wm*64 + m*16 + row)*FF + f0 + wn*32 + c4) = vv;
      }
    }
    asm volatile("" ::: "memory");
  }
}

// ---------------- MFMA A-scale (one-time): As = R^T @ Om, double-buffered ----------
__global__ __launch_bounds__(256) void k_ascalem(
    const unsigned short* __restrict__ OmbT, const unsigned short* __restrict__ Rbt,
    unsigned short* __restrict__ As)
{
  __shared__ __align__(16) unsigned char lds[32768];   // 2 x 16 KiB
  int id = blockIdx.x;                 // 2048 = b(16) x f-tile(4) x t-tile(32)
  int b  = id >> 7;
  int f0 = ((id >> 5) & 3) * 128;
  int t0 = (id & 31) * 128;
  int tid  = threadIdx.x;
  int lane = tid & 63, wid = tid >> 6;
  int lr = lane & 15, lg = lane >> 4;
  int wm = wid >> 1, wn = wid & 1;

  f32x4 acc[4][4];
  #pragma unroll
  for (int m=0;m<4;++m)
    #pragma unroll
    for (int n=0;n<4;++n)
      #pragma unroll
      for (int i=0;i<4;++i) acc[m][n][i]=0.0f;

  int swz  = ((lg ^ (lr & 3) ^ ((lr >> 2) & 3)) << 4);
  int aoff = (wm*64 + lr)*64 + swz;
  int boff = 8192 + (wn*64 + lr)*64 + swz;
  int c0 = tid, c1 = tid + 256;
  int r0 = c0 >> 2, s0 = c0 & 3;
  int r1 = c1 >> 2, s1 = c1 & 3;
  const unsigned short* gA0 = OmbT + ((size_t)b*TT + t0 + r0)*EE + ssw(r0,s0);
  const unsigned short* gA1 = OmbT + ((size_t)b*TT + t0 + r1)*EE + ssw(r1,s1);
  const unsigned short* gB0 = Rbt  + ((size_t)(b*FF + f0 + r0))*EE + ssw(r0,s0);
  const unsigned short* gB1 = Rbt  + ((size_t)(b*FF + f0 + r1))*EE + ssw(r1,s1);

  gld16(gA0, lds + c0*16);
  gld16(gA1, lds + c1*16);
  gld16(gB0, lds + 8192 + c0*16);
  gld16(gB1, lds + 8192 + c1*16);
  #pragma unroll
  for (int kk=0; kk<8; ++kk){
    int cur = (kk&1)*16384;
    if (kk < 7){
      int nxt = ((kk+1)&1)*16384;
      int eoff = (kk+1)*32;
      gld16(gA0 + eoff, lds + nxt + c0*16);
      gld16(gA1 + eoff, lds + nxt + c1*16);
      gld16(gB0 + eoff, lds + nxt + 8192 + c0*16);
      gld16(gB1 + eoff, lds + nxt + 8192 + c1*16);
      asm volatile("s_waitcnt vmcnt(4)" ::: "memory");
    } else {
      asm volatile("s_waitcnt vmcnt(0)" ::: "memory");
    }
    __syncthreads();
    bf16x8 af[4], bb[4];
    #pragma unroll
    for (int m=0;m<4;++m) af[m] = *(const bf16x8*)(lds + cur + aoff + m*1024);
    #pragma unroll
    for (int n=0;n<4;++n) bb[n] = *(const bf16x8*)(lds + cur + boff + n*1024);
    #pragma unroll
    for (int m=0;m<4;++m)
      #pragma unroll
      for (int n=0;n<4;++n)
        acc[m][n] = __builtin_amdgcn_mfma_f32_16x16x32_bf16(af[m], bb[n], acc[m][n], 0, 0, 0);
    __syncthreads();
  }

  #pragma unroll
  for (int m=0;m<4;++m){
    int tq = wm*64 + m*16 + lg*4;
    #pragma unroll
    for (int n=0;n<4;++n){
      int floc = wn*64 + n*16 + lr;
      size_t off = ((size_t)(b*FF + f0 + floc))*TT + t0 + tq;
      ushort4 o;
      o.x = f2bf(acc[m][n][0]); o.y = f2bf(acc[m][n][1]);
      o.z = f2bf(acc[m][n][2]); o.w = f2bf(acc[m][n][3]);
      *(ushort4*)(As + off) = o;       // integer counts <=256, exact in bf16
    }
  }
}

// ---------------- launch ----------------

extern "C" void kernel_launch(void* const* d_in, const int* in_sizes, int n_in,
                              void* d_out, int out_size, void* d_ws, size_t ws_size,
                              hipStream_t stream){
  const float* Y   = (const float*)d_in[0];
  const float* Rm  = (const float*)d_in[1];
  const float* Om  = (const float*)d_in[2];
  const float* P0  = (const float*)d_in[3];
  const float* Q0  = (const float*)d_in[4];
  const float* lam = (const float*)d_in[5];
  const float* mu  = (const float*)d_in[6];
  const float* nu  = (const float*)d_in[7];
  const float* gl  = (const float*)d_in[8];
  float* A = (float*)d_out;

  char* ws = (char*)d_ws;
  const size_t X_OFF    = 0;                               // Xb bf16 [e][t]: 32 MiB (64 reserved)
  const size_t REST_OFF = X_OFF    + (size_t)BB*EE*TT*4;
  const size_t OMB_OFF  = REST_OFF + (size_t)BB*TT*EE*2;   // residT bf16 [t][e]: 32 MiB
  const size_t AS_OFF   = OMB_OFF  + (size_t)BB*EE*TT*2;   // Omb bf16: 32 MiB
  const size_t QT_OFF   = AS_OFF   + (size_t)BB*FF*TT*2;   // As bf16: 64 MiB
  const size_t P_OFF    = QT_OFF   + (size_t)BB*RK*TT*4;
  const size_t LHS_OFF  = P_OFF    + (size_t)BB*EE*RK*4;
  const size_t INV_OFF  = LHS_OFF  + (size_t)BB*RK*RK*4;
  const size_t PRM_OFF  = INV_OFF  + (size_t)BB*RK*RK*4;
  const size_t RB_OFF   = PRM_OFF  + 4096;                 // Rb bf16 [e][f]: 4 MiB
  const size_t RBT_OFF  = RB_OFF   + (size_t)BB*EE*FF*2;   // Rbt bf16 [f][e]: 4 MiB
  const size_t OMBT_OFF = RBT_OFF  + (size_t)BB*FF*EE*2;   // OmbT bf16 [t][e]: 32 MiB
  const size_t ABT_OFF  = OMBT_OFF + (size_t)BB*TT*EE*2;   // Abt bf16 [t][f]: 64 MiB
  const size_t OBIT_OFF = ABT_OFF  + (size_t)BB*TT*FF*2;   // Ombit: 2 MiB

  unsigned short* Xb     = (unsigned short*)(ws + X_OFF);
  unsigned short* residT = (unsigned short*)(ws + REST_OFF);
  unsigned short* Omb    = (unsigned short*)(ws + OMB_OFF);
  unsigned short* As     = (unsigned short*)(ws + AS_OFF);
  float* Qt   = (float*)(ws + QT_OFF);
  float* P    = (float*)(ws + P_OFF);
  float* lhs  = (float*)(ws + LHS_OFF);
  float* inv  = (float*)(ws + INV_OFF);
  float* prm  = (float*)(ws + PRM_OFF);
  unsigned short* Rb    = (unsigned short*)(ws + RB_OFF);
  unsigned short* Rbt   = (unsigned short*)(ws + RBT_OFF);
  unsigned short* OmbT  = (unsigned short*)(ws + OMBT_OFF);
  unsigned short* Abt   = (unsigned short*)(ws + ABT_OFF);
  unsigned int*   Ombit = (unsigned int*)(ws + OBIT_OFF);

  (void)P0; (void)in_sizes; (void)n_in; (void)ws_size;

  hipMemsetAsync(d_out, 0, (size_t)out_size*sizeof(float), stream);
  k_params<<<1, 64, 0, stream>>>(lam, mu, nu, gl, prm);
  k_initX<<<BB*EE*TT/4/256, 256, 0, stream>>>((const float4*)Y, (const float4*)Om,
                                              (ushort4*)Xb, (ushort4*)Omb);
  k_ombit<<<BB*EE*TT/8192, 256, 0, stream>>>(Om, Ombit);
  k_qtrans<<<BB*TT/256, 256, 0, stream>>>(Q0, Qt);
  k_rbf<<<BB*EE*FF/4/256, 256, 0, stream>>>((const float4*)Rm, (ushort4*)Rb);
  k_rtransb<<<dim3(FF, BB), 256, 0, stream>>>(Rm, Rbt);
  k_omtrans<<<dim3(TT/64, EE/64, BB), 256, 0, stream>>>(Omb, OmbT);
  k_ascalem<<<2048, 256, 0, stream>>>(OmbT, Rbt, As);

  for (int k=0; k<NIT; ++k){
    k_lhsQ  <<<dim3(55, BB), 256, 0, stream>>>(Qt, prm, lhs, k);
    k_invert<<<BB, 256, 0, stream>>>(lhs, inv);
    k_Pupd  <<<dim3(EE, BB), 256, 0, stream>>>(Xb, Qt, inv, P);
    k_lhsP  <<<dim3(55, BB), 256, 0, stream>>>(P, prm, lhs, k);
    k_invert<<<BB, 256, 0, stream>>>(lhs, inv);
    k_Qupd  <<<dim3(TT/256, BB), 256, 0, stream>>>(Xb, P, inv, Qt);
    k_gemm1m<<<2048, 256, 0, stream>>>(Abt, Rb, Y, Ombit, Qt, P, prm, Xb, residT, k);
    k_gemm2m<<<4096, 256, 0, stream>>>(residT, Rbt, As, prm, A, Abt, k);
  }
}

// Round 6
// 1786.305 us; speedup vs baseline: 1.0345x; 1.0345x over previous
//
#include <hip/hip_runtime.h>
#include <stdint.h>

#define BB 16
#define EE 256
#define TT 4096
#define FF 512
#define RK 10
#define NIT 5

typedef short bf16x8 __attribute__((ext_vector_type(8)));
typedef float f32x4  __attribute__((ext_vector_type(4)));

__device__ __forceinline__ unsigned short f2bf(float x){
  unsigned int u = __float_as_uint(x);
  unsigned int r = (u + 0x7FFFu + ((u >> 16) & 1u)) >> 16;
  return (unsigned short)r;
}
__device__ __forceinline__ float bf2f(unsigned short s){
  return __uint_as_float(((unsigned int)s) << 16);
}

// async global->LDS, 16B per lane; LDS dest linear in lane order.
__device__ __forceinline__ void gld16(const void* g, void* l){
  __builtin_amdgcn_global_load_lds((const __attribute__((address_space(1))) unsigned int*)g,
                                   (__attribute__((address_space(3))) unsigned int*)l,
                                   16, 0, 0);
}

// slot swizzle (involution): source slot for (row r, phys slot s), ushort units
__device__ __forceinline__ int ssw(int r, int s){
  return ((s ^ (r & 3) ^ ((r >> 2) & 3)) << 3);
}

// ---------------- setup kernels ----------------

__global__ void k_params(const float* lam_log, const float* mu_log,
                         const float* nu_log, const float* gl, float* prm){
  int k = threadIdx.x;
  if (k < NIT){
    float lam = expf(lam_log[k]);
    float mu  = expf(mu_log[k]);
    float nu  = expf(nu_log[k]);
    float gam = 1.0f/(1.0f+expf(-gl[k]));
    prm[k*8+0]=lam; prm[k*8+1]=mu; prm[k*8+2]=nu; prm[k*8+3]=gam; prm[k*8+4]=lam/nu;
  }
}

// Xb = bf16(Om*Y)
__global__ void k_initX(const float4* __restrict__ Y, const float4* __restrict__ Om,
                        ushort4* __restrict__ Xb){
  int i = blockIdx.x*256 + threadIdx.x;
  float4 y = Y[i], o = Om[i];
  ushort4 xb; xb.x=f2bf(y.x*o.x); xb.y=f2bf(y.y*o.y); xb.z=f2bf(y.z*o.z); xb.w=f2bf(y.w*o.w);
  Xb[i] = xb;
}

// Omega -> 1 bit/elem, [b][e][t] order, little-endian within u32 word
__global__ void k_ombit(const float* __restrict__ Om, unsigned int* __restrict__ Ombit){
  int tid = threadIdx.x;
  int wv = tid >> 6, lane = tid & 63;
  size_t base = (size_t)blockIdx.x*8192 + (size_t)wv*2048;
  for (int it=0; it<32; ++it){
    float om = Om[base + it*64 + lane];
    unsigned long long m = __ballot(om != 0.0f);
    if (lane==0)  Ombit[(base>>5) + it*2]     = (unsigned int)m;
    if (lane==32) Ombit[(base>>5) + it*2 + 1] = (unsigned int)(m>>32);
  }
}

__global__ void k_qtrans(const float* __restrict__ Q0, float* __restrict__ Qt){
  int idx = blockIdx.x*256 + threadIdx.x;   // b*TT + t
  int b = idx >> 12, t = idx & (TT-1);
  #pragma unroll
  for (int j=0;j<RK;j++)
    Qt[((size_t)b*RK + j)*TT + t] = Q0[(size_t)idx*RK + j];
}

// R -> bf16 [e][f] (binary, exact)  (B-operand of gemm1m)
__global__ void k_rbf(const float4* __restrict__ R, ushort4* __restrict__ Rb){
  int i = blockIdx.x*256 + threadIdx.x;
  float4 v = R[i];
  ushort4 o; o.x=f2bf(v.x); o.y=f2bf(v.y); o.z=f2bf(v.z); o.w=f2bf(v.w);
  Rb[i] = o;
}

// R -> bf16 transposed [f][e]  (B-operand of gemm2m/ascalem)
__global__ void k_rtransb(const float* __restrict__ Rm, unsigned short* __restrict__ Rbt){
  int f = blockIdx.x, b = blockIdx.y, e = threadIdx.x;
  Rbt[((size_t)b*FF + f)*EE + e] = f2bf(Rm[((size_t)b*EE + e)*FF + f]);
}

// Om fp32 [e][t] -> OmbT bf16 [t][e], 64x64 tile transpose (one-time)
__global__ void k_omtrans(const float* __restrict__ Om,
                          unsigned short* __restrict__ OmbT){
  __shared__ unsigned short sT[64][66];
  int b  = blockIdx.z;
  int E0 = blockIdx.y*64, T0 = blockIdx.x*64;
  int tid = threadIdx.x;
  int fi = tid >> 4;          // 0..15
  int m  = tid & 15;
  #pragma unroll
  for (int pass=0; pass<4; ++pass){
    int e = pass*16 + fi;
    float4 v = *(const float4*)(Om + ((size_t)(b*EE + E0 + e))*TT + T0 + m*4);
    sT[e][m*4+0]=f2bf(v.x); sT[e][m*4+1]=f2bf(v.y);
    sT[e][m*4+2]=f2bf(v.z); sT[e][m*4+3]=f2bf(v.w);
  }
  __syncthreads();
  #pragma unroll
  for (int pass=0; pass<4; ++pass){
    int t  = pass*16 + fi;
    int e4 = m*4;
    ushort4 o;
    o.x = sT[e4+0][t]; o.y = sT[e4+1][t];
    o.z = sT[e4+2][t]; o.w = sT[e4+3][t];
    *(ushort4*)(OmbT + ((size_t)b*TT + T0 + t)*EE + E0 + e4) = o;
  }
}

// ---------------- per-iteration small kernels ----------------

__global__ void k_lhsQ(const float* __restrict__ Qt, const float* __restrict__ prm,
                       float* __restrict__ lhs, int k){
  int p = blockIdx.x, b = blockIdx.y;
  int i = 0, rem = p;
  while (rem >= i+1){ rem -= (i+1); ++i; }
  int j = rem;
  const float* qi = Qt + ((size_t)b*RK + i)*TT;
  const float* qj = Qt + ((size_t)b*RK + j)*TT;
  float a = 0.0f;
  for (int t = threadIdx.x*4; t < TT; t += 1024){
    float4 x = *(const float4*)(qi+t);
    float4 y = *(const float4*)(qj+t);
    a += x.x*y.x + x.y*y.y + x.z*y.z + x.w*y.w;
  }
  __shared__ float red[256];
  red[threadIdx.x] = a; __syncthreads();
  for (int s=128; s>0; s>>=1){
    if (threadIdx.x < s) red[threadIdx.x] += red[threadIdx.x+s];
    __syncthreads();
  }
  if (threadIdx.x==0){
    float v = red[0];
    if (i==j) v += prm[k*8+4];
    lhs[(b*RK+i)*RK + j] = v;
    lhs[(b*RK+j)*RK + i] = v;
  }
}

__global__ void k_lhsP(const float* __restrict__ P, const float* __restrict__ prm,
                       float* __restrict__ lhs, int k){
  int p = blockIdx.x, b = blockIdx.y;
  int i = 0, rem = p;
  while (rem >= i+1){ rem -= (i+1); ++i; }
  int j = rem;
  int e = threadIdx.x;
  const float* pr = P + ((size_t)b*EE + e)*RK;
  float a = pr[i]*pr[j];
  __shared__ float red[256];
  red[threadIdx.x] = a; __syncthreads();
  for (int s=128; s>0; s>>=1){
    if (threadIdx.x < s) red[threadIdx.x] += red[threadIdx.x+s];
    __syncthreads();
  }
  if (threadIdx.x==0){
    float v = red[0];
    if (i==j) v += prm[k*8+4];
    lhs[(b*RK+i)*RK + j] = v;
    lhs[(b*RK+j)*RK + i] = v;
  }
}

__global__ void k_invert(const float* __restrict__ lhs, float* __restrict__ inv){
  int b = blockIdx.x;
  __shared__ float aug[RK][2*RK];
  int tid = threadIdx.x;
  int i = tid / (2*RK), j = tid % (2*RK);
  bool act = tid < RK*2*RK;
  if (act) aug[i][j] = (j < RK) ? lhs[(b*RK+i)*RK + j] : ((j-RK)==i ? 1.0f : 0.0f);
  __syncthreads();
  for (int kk=0; kk<RK; ++kk){
    float pinv = 1.0f / aug[kk][kk];
    __syncthreads();
    if (act && i==kk) aug[i][j] *= pinv;
    __syncthreads();
    float factor = (act && i!=kk) ? aug[i][kk] : 0.0f;
    float pivrow = act ? aug[kk][j] : 0.0f;
    __syncthreads();
    if (act && i!=kk) aug[i][j] -= factor * pivrow;
    __syncthreads();
  }
  if (act && j >= RK) inv[(b*RK+i)*RK + (j-RK)] = aug[i][j];
}

// Pupd: P = (X@Q)@inv, X read as bf16 [e][t]
__global__ void k_Pupd(const unsigned short* __restrict__ Xb, const float* __restrict__ Qt,
                       const float* __restrict__ inv, float* __restrict__ P){
  int e = blockIdx.x, b = blockIdx.y;
  const unsigned short* xr = Xb + ((size_t)b*EE + e)*TT;
  const float* qb = Qt + (size_t)b*RK*TT;
  float acc[RK];
  #pragma unroll
  for (int j=0;j<RK;j++) acc[j]=0.0f;
  for (int t = threadIdx.x*8; t < TT; t += 2048){
    bf16x8 xv = *(const bf16x8*)(xr+t);
    float xf[8];
    #pragma unroll
    for (int i=0;i<8;++i) xf[i] = bf2f((unsigned short)xv[i]);
    #pragma unroll
    for (int j=0;j<RK;j++){
      float4 qa = *(const float4*)(qb + (size_t)j*TT + t);
      float4 qc = *(const float4*)(qb + (size_t)j*TT + t + 4);
      acc[j] += xf[0]*qa.x + xf[1]*qa.y + xf[2]*qa.z + xf[3]*qa.w
              + xf[4]*qc.x + xf[5]*qc.y + xf[6]*qc.z + xf[7]*qc.w;
    }
  }
  __shared__ float partial[4][RK];
  int lane = threadIdx.x & 63, wv = threadIdx.x >> 6;
  #pragma unroll
  for (int j=0;j<RK;j++){
    float v = acc[j];
    for (int s=32;s>0;s>>=1) v += __shfl_down(v, s, 64);
    if (lane==0) partial[wv][j] = v;
  }
  __syncthreads();
  if (threadIdx.x < RK){
    int i = threadIdx.x;
    float out = 0.0f;
    #pragma unroll
    for (int j=0;j<RK;j++){
      float xq = partial[0][j]+partial[1][j]+partial[2][j]+partial[3][j];
      out += xq * inv[(b*RK+j)*RK + i];
    }
    P[((size_t)b*EE + e)*RK + i] = out;
  }
}

// Qupd: Q = (X^T@P)@inv, X read as bf16
__global__ void k_Qupd(const unsigned short* __restrict__ Xb, const float* __restrict__ P,
                       const float* __restrict__ inv, float* __restrict__ Qt){
  int b = blockIdx.y;
  int t = blockIdx.x*256 + threadIdx.x;
  __shared__ float sP[EE*RK];
  __shared__ float sInv[RK*RK];
  for (int i=threadIdx.x; i<EE*RK; i+=256) sP[i] = P[(size_t)b*EE*RK + i];
  if (threadIdx.x < RK*RK) sInv[threadIdx.x] = inv[b*RK*RK + threadIdx.x];
  __syncthreads();
  float acc[RK];
  #pragma unroll
  for (int j=0;j<RK;j++) acc[j]=0.0f;
  const unsigned short* xb = Xb + (size_t)b*EE*TT + t;
  for (int e=0;e<EE;e++){
    float x = bf2f(xb[(size_t)e*TT]);
    #pragma unroll
    for (int j=0;j<RK;j++) acc[j] += x * sP[e*RK+j];
  }
  #pragma unroll
  for (int i=0;i<RK;i++){
    float q = 0.0f;
    #pragma unroll
    for (int j=0;j<RK;j++) q += acc[j]*sInv[j*RK+i];
    Qt[((size_t)b*RK + i)*TT + t] = q;
  }
}

// ---------------- fused MFMA gemm1 (M=t 64, N=e 128), single-buffer K-loop ----
// A-operand = Abt [t][f], B-operand = Rb [e][f]; D[t][e] = RA[e][t].
// Writes Xb bf16 [e][t] (skipped at last iter) and residT bf16 [t][e].
__global__ __launch_bounds__(256) void k_gemm1m(
    const unsigned short* __restrict__ Abt, const unsigned short* __restrict__ Rb,
    const float* __restrict__ Y, const unsigned int* __restrict__ Ombit,
    const float* __restrict__ Qt, const float* __restrict__ P,
    const float* __restrict__ prm, unsigned short* __restrict__ Xb,
    unsigned short* __restrict__ residT, int k)
{
  __shared__ __align__(16) unsigned char lds[20480];
  int id = blockIdx.x;                 // 2048 = b(16) x e-tile(2) x t-tile(64)
  int b  = id >> 7;
  int e0 = ((id >> 6) & 1) * 128;
  int t0 = (id & 63) * 64;
  int tid  = threadIdx.x;
  int lane = tid & 63, wid = tid >> 6;
  int lr = lane & 15, lg = lane >> 4;
  int wm = wid >> 1, wn = wid & 1;     // wm: t-half(32), wn: e-half(64)

  f32x4 acc[2][4];
  #pragma unroll
  for (int m=0;m<2;++m)
    #pragma unroll
    for (int n=0;n<4;++n)
      #pragma unroll
      for (int i=0;i<4;++i) acc[m][n][i]=0.0f;

  if (k > 0){
    int swz  = ((lg ^ (lr & 3) ^ ((lr >> 2) & 3)) << 4);
    int aoff = (wm*32 + lr)*64 + swz;            // A region: 64 t-rows @ 0
    int boff = 4096 + (wn*64 + lr)*64 + swz;     // B region: 128 e-rows @ 4096
    int rA = tid >> 2, sA = tid & 3;             // A: 256 chunks
    int c0 = tid, c1 = tid + 256;                // B: 512 chunks
    int rB0 = c0 >> 2, sB0 = c0 & 3;
    int rB1 = c1 >> 2, sB1 = c1 & 3;
    const unsigned short* gA  = Abt + ((size_t)b*TT + t0 + rA)*FF + ssw(rA,sA);
    const unsigned short* gB0 = Rb  + ((size_t)(b*EE + e0 + rB0))*FF + ssw(rB0,sB0);
    const unsigned short* gB1 = Rb  + ((size_t)(b*EE + e0 + rB1))*FF + ssw(rB1,sB1);
    unsigned char* lA  = lds + tid*16;
    unsigned char* lB0 = lds + 4096 + c0*16;
    unsigned char* lB1 = lds + 4096 + c1*16;

    for (int kk=0; kk<16; ++kk){
      __syncthreads();
      int f0k = kk*32;
      gld16(gA  + f0k, lA);
      gld16(gB0 + f0k, lB0);
      gld16(gB1 + f0k, lB1);
      asm volatile("s_waitcnt vmcnt(0)" ::: "memory");
      __syncthreads();
      bf16x8 af[2], bb[4];
      #pragma unroll
      for (int m=0;m<2;++m) af[m] = *(const bf16x8*)(lds + aoff + m*1024);
      #pragma unroll
      for (int n=0;n<4;++n) bb[n] = *(const bf16x8*)(lds + boff + n*1024);
      #pragma unroll
      for (int m=0;m<2;++m)
        #pragma unroll
        for (int n=0;n<4;++n)
          acc[m][n] = __builtin_amdgcn_mfma_f32_16x16x32_bf16(af[m], bb[n], acc[m][n], 0, 0, 0);
    }
  }

  // epilogue: wbuf [16][68] ushort per wave (reuses staging LDS); P/Q at top.
  __syncthreads();
  unsigned short* wbuf = (unsigned short*)(lds + wid*2176);
  float* Pl = (float*)(lds + 12288);           // [128][RK]
  float* Ql = (float*)(lds + 12288 + 5120);    // [RK][64]
  for (int idx = tid; idx < 128*RK; idx += 256)
    Pl[idx] = P[((size_t)(b*EE + e0))*RK + idx];
  for (int idx = tid; idx < RK*64; idx += 256){
    int j = idx >> 6, t = idx & 63;
    Ql[idx] = Qt[((size_t)(b*RK + j))*TT + t0 + t];
  }
  __syncthreads();

  float nu = prm[k*8+2];
  bool wx = (k < NIT-1);
  #pragma unroll
  for (int m=0;m<2;++m){
    int tq = wm*32 + m*16 + lg*4;                // t offset within 64-tile
    float4 ql4[RK];
    #pragma unroll
    for (int j=0;j<RK;++j) ql4[j] = *(const float4*)(Ql + j*64 + tq);
    asm volatile("" ::: "memory");
    #pragma unroll
    for (int n=0;n<4;++n){
      int eloc = wn*64 + n*16 + lr;
      const float* pr = Pl + eloc*RK;
      float4 pq = {0,0,0,0};
      #pragma unroll
      for (int j=0;j<RK;++j){
        float pj = pr[j];
        pq.x += pj*ql4[j].x; pq.y += pj*ql4[j].y;
        pq.z += pj*ql4[j].z; pq.w += pj*ql4[j].w;
      }
      f32x4 ra = acc[m][n];
      size_t off = ((size_t)(b*EE + e0 + eloc))*TT + t0 + tq;
      float4 y = *(const float4*)(Y + off);
      unsigned int w = Ombit[off >> 5];
      int sh = (int)(off & 31);                  // tq aligned to 4, t0 to 64
      float rs0, rs1, rs2, rs3; ushort4 xb4;
      {
        float om2 = (w>>(sh+0))&1 ? 1.0f : 0.0f; float d = y.x - ra[0];
        float x = (om2*d + nu*pq.x)/(om2 + nu); rs0 = om2*(y.x - x - ra[0]); xb4.x = f2bf(x);
      }{
        float om2 = (w>>(sh+1))&1 ? 1.0f : 0.0f; float d = y.y - ra[1];
        float x = (om2*d + nu*pq.y)/(om2 + nu); rs1 = om2*(y.y - x - ra[1]); xb4.y = f2bf(x);
      }{
        float om2 = (w>>(sh+2))&1 ? 1.0f : 0.0f; float d = y.z - ra[2];
        float x = (om2*d + nu*pq.z)/(om2 + nu); rs2 = om2*(y.z - x - ra[2]); xb4.z = f2bf(x);
      }{
        float om2 = (w>>(sh+3))&1 ? 1.0f : 0.0f; float d = y.w - ra[3];
        float x = (om2*d + nu*pq.w)/(om2 + nu); rs3 = om2*(y.w - x - ra[3]); xb4.w = f2bf(x);
      }
      if (wx) *(ushort4*)(Xb + off) = xb4;
      int wc = n*16 + lr;
      wbuf[(lg*4+0)*68 + wc] = f2bf(rs0);
      wbuf[(lg*4+1)*68 + wc] = f2bf(rs1);
      wbuf[(lg*4+2)*68 + wc] = f2bf(rs2);
      wbuf[(lg*4+3)*68 + wc] = f2bf(rs3);
    }
    asm volatile("" ::: "memory");
    // readback: 16 t-rows x 64 e, coalesced 128B rows
    #pragma unroll
    for (int j2=0;j2<4;++j2){
      int row = j2*4 + lg;
      int c4  = lr*4;
      ushort4 vv = *(const ushort4*)(wbuf + row*68 + c4);
      *(ushort4*)(residT + ((size_t)b*TT + t0 + wm*32 + m*16 + row)*EE + e0 + wn*64 + c4) = vv;
    }
    asm volatile("" ::: "memory");
  }
}

__device__ __forceinline__ float aupd(float a, float g, unsigned short asu,
                                      float mu, float gamma){
  float as = bf2f(asu);
  bool no = (as == 0.0f);
  float rs = 1.0f / (no ? 1.0f : as);
  float ba = a + g*rs;
  float ad = copysignf(fmaxf(fabsf(ba) - mu*rs, 0.0f), ba);
  if (no) ad = 0.0f;
  return a + gamma*(ad - a);
}

// ---------------- MFMA gemm2 (M=t 128, N=f 64), single-buffer K-loop ----------
// A-operand = residT [t][e], B-operand = Rbt [f][e]; D[t][f] = G[f][t].
// A state kept bf16: read Abf [f][t] (k>0), write Abf + Abt [t][f] (k<last),
// final iteration writes fp32 A to d_out only.
__global__ __launch_bounds__(256) void k_gemm2m(
    const unsigned short* __restrict__ residT, const unsigned short* __restrict__ Rbt,
    const unsigned short* __restrict__ As, const float* __restrict__ prm,
    unsigned short* __restrict__ Abf, unsigned short* __restrict__ Abt,
    float* __restrict__ Afin, int k)
{
  __shared__ __align__(16) unsigned char lds[12288];
  int id = blockIdx.x;                 // 4096 = b(16) x f-tile(8) x t-tile(32)
  int b  = id >> 8;
  int f0 = ((id >> 5) & 7) * 64;
  int t0 = (id & 31) * 128;
  int tid  = threadIdx.x;
  int lane = tid & 63, wid = tid >> 6;
  int lr = lane & 15, lg = lane >> 4;
  int wm = wid >> 1, wn = wid & 1;     // wm: t-half(64), wn: f-half(32)

  f32x4 acc[4][2];
  #pragma unroll
  for (int m=0;m<4;++m)
    #pragma unroll
    for (int n=0;n<2;++n)
      #pragma unroll
      for (int i=0;i<4;++i) acc[m][n][i]=0.0f;

  int swz  = ((lg ^ (lr & 3) ^ ((lr >> 2) & 3)) << 4);
  int aoff = (wm*64 + lr)*64 + swz;            // A region: 128 t-rows @ 0
  int boff = 8192 + (wn*32 + lr)*64 + swz;     // B region: 64 f-rows @ 8192
  int c0 = tid, c1 = tid + 256;                // A: 512 chunks
  int r0 = c0 >> 2, s0 = c0 & 3;
  int r1 = c1 >> 2, s1 = c1 & 3;
  int rB = tid >> 2, sB = tid & 3;             // B: 256 chunks
  const unsigned short* gA0 = residT + ((size_t)b*TT + t0 + r0)*EE + ssw(r0,s0);
  const unsigned short* gA1 = residT + ((size_t)b*TT + t0 + r1)*EE + ssw(r1,s1);
  const unsigned short* gB  = Rbt    + ((size_t)(b*FF + f0 + rB))*EE + ssw(rB,sB);
  unsigned char* lA0 = lds + c0*16;
  unsigned char* lA1 = lds + c1*16;
  unsigned char* lB  = lds + 8192 + tid*16;

  for (int kk=0; kk<8; ++kk){
    __syncthreads();
    int eoff = kk*32;
    gld16(gA0 + eoff, lA0);
    gld16(gA1 + eoff, lA1);
    gld16(gB  + eoff, lB);
    asm volatile("s_waitcnt vmcnt(0)" ::: "memory");
    __syncthreads();
    bf16x8 af[4], bb[2];
    #pragma unroll
    for (int m=0;m<4;++m) af[m] = *(const bf16x8*)(lds + aoff + m*1024);
    #pragma unroll
    for (int n=0;n<2;++n) bb[n] = *(const bf16x8*)(lds + boff + n*1024);
    #pragma unroll
    for (int m=0;m<4;++m)
      #pragma unroll
      for (int n=0;n<2;++n)
        acc[m][n] = __builtin_amdgcn_mfma_f32_16x16x32_bf16(af[m], bb[n], acc[m][n], 0, 0, 0);
  }

  __syncthreads();                      // staging LDS reused as wbuf below
  unsigned short* wbuf = (unsigned short*)(lds + wid*1152);   // [16][36]
  float mu = prm[k*8+1], gamma = prm[k*8+3];
  bool emit = (k < NIT-1);              // intermediate: keep state bf16
  #pragma unroll
  for (int m=0;m<4;++m){
    int tq = wm*64 + m*16 + lg*4;
    #pragma unroll
    for (int n=0;n<2;++n){
      int floc = wn*32 + n*16 + lr;
      size_t off = ((size_t)(b*FF + f0 + floc))*TT + t0 + tq;
      float4 a;
      if (k > 0){
        ushort4 ab4 = *(const ushort4*)(Abf + off);
        a.x = bf2f(ab4.x); a.y = bf2f(ab4.y); a.z = bf2f(ab4.z); a.w = bf2f(ab4.w);
      } else {
        a = make_float4(0.f, 0.f, 0.f, 0.f);
      }
      ushort4 as4 = *(const ushort4*)(As + off);
      f32x4 g = acc[m][n];
      float4 an;
      an.x = aupd(a.x, g[0], as4.x, mu, gamma);
      an.y = aupd(a.y, g[1], as4.y, mu, gamma);
      an.z = aupd(a.z, g[2], as4.z, mu, gamma);
      an.w = aupd(a.w, g[3], as4.w, mu, gamma);
      if (emit){
        ushort4 ab;
        ab.x = f2bf(an.x); ab.y = f2bf(an.y); ab.z = f2bf(an.z); ab.w = f2bf(an.w);
        *(ushort4*)(Abf + off) = ab;
        int wc = n*16 + lr;
        wbuf[(lg*4+0)*36 + wc] = ab.x;
        wbuf[(lg*4+1)*36 + wc] = ab.y;
        wbuf[(lg*4+2)*36 + wc] = ab.z;
        wbuf[(lg*4+3)*36 + wc] = ab.w;
      } else {
        *(float4*)(Afin + off) = an;    // final fp32 output, covers all of A
      }
    }
    asm volatile("" ::: "memory");
    if (emit){
      // readback: 16 t-rows x 32 f, 2 passes of 8 rows x 8 lanes
      #pragma unroll
      for (int j2=0;j2<2;++j2){
        int row = j2*8 + (lane >> 3);
        int c4  = (lane & 7)*4;
        ushort4 vv = *(const ushort4*)(wbuf + row*36 + c4);
        *(ushort4*)(Abt + ((size_t)b*TT + t0 + wm*64 + m*16 + row)*FF + f0 + wn*32 + c4) = vv;
      }
    }
    asm volatile("" ::: "memory");
  }
}

// ---------------- MFMA A-scale (one-time): As = R^T @ Om, single-buffer ----------
__global__ __launch_bounds__(256) void k_ascalem(
    const unsigned short* __restrict__ OmbT, const unsigned short* __restrict__ Rbt,
    unsigned short* __restrict__ As)
{
  __shared__ __align__(16) unsigned char lds[16384];
  int id = blockIdx.x;                 // 2048 = b(16) x f-tile(4) x t-tile(32)
  int b  = id >> 7;
  int f0 = ((id >> 5) & 3) * 128;
  int t0 = (id & 31) * 128;
  int tid  = threadIdx.x;
  int lane = tid & 63, wid = tid >> 6;
  int lr = lane & 15, lg = lane >> 4;
  int wm = wid >> 1, wn = wid & 1;

  f32x4 acc[4][4];
  #pragma unroll
  for (int m=0;m<4;++m)
    #pragma unroll
    for (int n=0;n<4;++n)
      #pragma unroll
      for (int i=0;i<4;++i) acc[m][n][i]=0.0f;

  int swz  = ((lg ^ (lr & 3) ^ ((lr >> 2) & 3)) << 4);
  int aoff = (wm*64 + lr)*64 + swz;
  int boff = 8192 + (wn*64 + lr)*64 + swz;
  int c0 = tid, c1 = tid + 256;
  int r0 = c0 >> 2, s0 = c0 & 3;
  int r1 = c1 >> 2, s1 = c1 & 3;
  const unsigned short* gA0 = OmbT + ((size_t)b*TT + t0 + r0)*EE + ssw(r0,s0);
  const unsigned short* gA1 = OmbT + ((size_t)b*TT + t0 + r1)*EE + ssw(r1,s1);
  const unsigned short* gB0 = Rbt  + ((size_t)(b*FF + f0 + r0))*EE + ssw(r0,s0);
  const unsigned short* gB1 = Rbt  + ((size_t)(b*FF + f0 + r1))*EE + ssw(r1,s1);
  unsigned char* lA0 = lds + c0*16;
  unsigned char* lA1 = lds + c1*16;
  unsigned char* lB0 = lds + 8192 + c0*16;
  unsigned char* lB1 = lds + 8192 + c1*16;

  for (int kk=0; kk<8; ++kk){
    __syncthreads();
    int eoff = kk*32;
    gld16(gA0 + eoff, lA0);
    gld16(gA1 + eoff, lA1);
    gld16(gB0 + eoff, lB0);
    gld16(gB1 + eoff, lB1);
    asm volatile("s_waitcnt vmcnt(0)" ::: "memory");
    __syncthreads();
    bf16x8 af[4], bb[4];
    #pragma unroll
    for (int m=0;m<4;++m) af[m] = *(const bf16x8*)(lds + aoff + m*1024);
    #pragma unroll
    for (int n=0;n<4;++n) bb[n] = *(const bf16x8*)(lds + boff + n*1024);
    #pragma unroll
    for (int m=0;m<4;++m)
      #pragma unroll
      for (int n=0;n<4;++n)
        acc[m][n] = __builtin_amdgcn_mfma_f32_16x16x32_bf16(af[m], bb[n], acc[m][n], 0, 0, 0);
  }

  #pragma unroll
  for (int m=0;m<4;++m){
    int tq = wm*64 + m*16 + lg*4;
    #pragma unroll
    for (int n=0;n<4;++n){
      int floc = wn*64 + n*16 + lr;
      size_t off = ((size_t)(b*FF + f0 + floc))*TT + t0 + tq;
      ushort4 o;
      o.x = f2bf(acc[m][n][0]); o.y = f2bf(acc[m][n][1]);
      o.z = f2bf(acc[m][n][2]); o.w = f2bf(acc[m][n][3]);
      *(ushort4*)(As + off) = o;       // integer counts <=256, exact in bf16
    }
  }
}

// ---------------- launch ----------------

extern "C" void kernel_launch(void* const* d_in, const int* in_sizes, int n_in,
                              void* d_out, int out_size, void* d_ws, size_t ws_size,
                              hipStream_t stream){
  const float* Y   = (const float*)d_in[0];
  const float* Rm  = (const float*)d_in[1];
  const float* Om  = (const float*)d_in[2];
  const float* P0  = (const float*)d_in[3];
  const float* Q0  = (const float*)d_in[4];
  const float* lam = (const float*)d_in[5];
  const float* mu  = (const float*)d_in[6];
  const float* nu  = (const float*)d_in[7];
  const float* gl  = (const float*)d_in[8];
  float* A = (float*)d_out;

  char* ws = (char*)d_ws;
  const size_t XB_OFF   = 0;                               // Xb bf16 [e][t]: 32 MiB
  const size_t REST_OFF = XB_OFF   + (size_t)BB*EE*TT*2;   // residT bf16 [t][e]: 32 MiB
  const size_t AS_OFF   = REST_OFF + (size_t)BB*TT*EE*2;   // As bf16 [f][t]: 64 MiB
  const size_t QT_OFF   = AS_OFF   + (size_t)BB*FF*TT*2;
  const size_t P_OFF    = QT_OFF   + (size_t)BB*RK*TT*4;
  const size_t LHS_OFF  = P_OFF    + (size_t)BB*EE*RK*4;
  const size_t INV_OFF  = LHS_OFF  + (size_t)BB*RK*RK*4;
  const size_t PRM_OFF  = INV_OFF  + (size_t)BB*RK*RK*4;
  const size_t RB_OFF   = PRM_OFF  + 4096;                 // Rb bf16 [e][f]: 4 MiB
  const size_t RBT_OFF  = RB_OFF   + (size_t)BB*EE*FF*2;   // Rbt bf16 [f][e]: 4 MiB
  const size_t OMBT_OFF = RBT_OFF  + (size_t)BB*FF*EE*2;   // OmbT bf16 [t][e]: 32 MiB
  const size_t ABT_OFF  = OMBT_OFF + (size_t)BB*TT*EE*2;   // Abt bf16 [t][f]: 64 MiB
  const size_t OBIT_OFF = ABT_OFF  + (size_t)BB*TT*FF*2;   // Ombit: 2 MiB
  const size_t ABF_OFF  = OBIT_OFF + (size_t)BB*EE*TT/8;   // Abf bf16 [f][t]: 64 MiB

  unsigned short* Xb     = (unsigned short*)(ws + XB_OFF);
  unsigned short* residT = (unsigned short*)(ws + REST_OFF);
  unsigned short* As     = (unsigned short*)(ws + AS_OFF);
  float* Qt   = (float*)(ws + QT_OFF);
  float* P    = (float*)(ws + P_OFF);
  float* lhs  = (float*)(ws + LHS_OFF);
  float* inv  = (float*)(ws + INV_OFF);
  float* prm  = (float*)(ws + PRM_OFF);
  unsigned short* Rb    = (unsigned short*)(ws + RB_OFF);
  unsigned short* Rbt   = (unsigned short*)(ws + RBT_OFF);
  unsigned short* OmbT  = (unsigned short*)(ws + OMBT_OFF);
  unsigned short* Abt   = (unsigned short*)(ws + ABT_OFF);
  unsigned int*   Ombit = (unsigned int*)(ws + OBIT_OFF);
  unsigned short* Abf   = (unsigned short*)(ws + ABF_OFF);

  (void)P0; (void)in_sizes; (void)n_in; (void)ws_size; (void)out_size;

  k_params<<<1, 64, 0, stream>>>(lam, mu, nu, gl, prm);
  k_initX<<<BB*EE*TT/4/256, 256, 0, stream>>>((const float4*)Y, (const float4*)Om,
                                              (ushort4*)Xb);
  k_ombit<<<BB*EE*TT/8192, 256, 0, stream>>>(Om, Ombit);
  k_qtrans<<<BB*TT/256, 256, 0, stream>>>(Q0, Qt);
  k_rbf<<<BB*EE*FF/4/256, 256, 0, stream>>>((const float4*)Rm, (ushort4*)Rb);
  k_rtransb<<<dim3(FF, BB), 256, 0, stream>>>(Rm, Rbt);
  k_omtrans<<<dim3(TT/64, EE/64, BB), 256, 0, stream>>>(Om, OmbT);
  k_ascalem<<<2048, 256, 0, stream>>>(OmbT, Rbt, As);

  for (int k=0; k<NIT; ++k){
    k_lhsQ  <<<dim3(55, BB), 256, 0, stream>>>(Qt, prm, lhs, k);
    k_invert<<<BB, 256, 0, stream>>>(lhs, inv);
    k_Pupd  <<<dim3(EE, BB), 256, 0, stream>>>(Xb, Qt, inv, P);
    k_lhsP  <<<dim3(55, BB), 256, 0, stream>>>(P, prm, lhs, k);
    k_invert<<<BB, 256, 0, stream>>>(lhs, inv);
    k_Qupd  <<<dim3(TT/256, BB), 256, 0, stream>>>(Xb, P, inv, Qt);
    k_gemm1m<<<2048, 256, 0, stream>>>(Abt, Rb, Y, Ombit, Qt, P, prm, Xb, residT, k);
    k_gemm2m<<<4096, 256, 0, stream>>>(residT, Rbt, As, prm, Abf, Abt, A, k);
  }
}